// Round 11
// baseline (154.818 us; speedup 1.0000x reference)
//
#include <hip/hip_runtime.h>
#include <math.h>

#define B_ 4
#define N_ 800
#define H_ 16

// ---- workspace layout (float indices) ----
#define WS_AP   0         // A' = h0*W1[:, :H] + b1      [4*800*16]
#define WS_BM   51200     // Bm = h0*W1[:, H:]           [4*800*16]
#define WS_P    102400    // P  = W3[:16,:]^T h0         [4*800*16]
#define WS_Q    153600    // Q  = W3[16:,:]^T h0         [4*800*16]
#define WS_D1   204800    // e - 2*c1                    [3200]
#define WS_D2   208000    // e - 2*c2                    [3200]
#define WS_S    211200    // BN sum  per channel i       [800]
#define WS_S2   212000    // BN sum2 per channel i       [800]
#define WS_SC   213072    // [0]=||b3||^2 [1]=sum(Wb)
#define WS_SS   213074    // sorted breakpoints          [16]
#define WS_WM   213090    // wm[k][h] = m*W2             [17*16]
#define WS_BMK  213362    // bm[k][h] = m*b2             [17*16]
#define WS_ABC  213634    // A,B,C,pad per interval      [17*4]
#define WS_PP   213702    // (PW,Pb) per (row,k)         [3200*17*2]
#define WS_QQ   322502    // (QW,Qb) per (row,k)         [3200*17*2]
#define WS_ACC  431302    // double loss accumulator (431302*4 % 8 == 0)
#define WS_TK   431304    // ticket counter (unsigned)

// ---------------- kernel 1: per-row prep + weight tables + ws zeroing ----------------
__global__ __launch_bounds__(256) void prep_k(
    const float* __restrict__ x, const float* __restrict__ W_enc,
    const float* __restrict__ b_enc, const float* __restrict__ W1,
    const float* __restrict__ b1, const float* __restrict__ Wb,
    const float* __restrict__ b3, const float* __restrict__ W3,
    const float* __restrict__ W2, const float* __restrict__ b2,
    float* __restrict__ ws) {
  int t = threadIdx.x;
  if (blockIdx.x == 14) {               // zero BN accumulators + ticket (ws poisoned)
    for (int i = t; i < 1600; i += 256) ws[WS_S + i] = 0.f;
    if (t == 0) *reinterpret_cast<unsigned*>(ws + WS_TK) = 0u;
    return;
  }
  if (blockIdx.x == 13) {               // weights-derived constants (whole block)
    __shared__ float sG[256], sR[16], sTB[16];
    __shared__ float sWM[272], sBMk[272];
    {
      int h = t >> 4, h2 = t & 15;
      float g = 0.f;
      #pragma unroll
      for (int o = 0; o < 32; ++o) g = fmaf(W3[o*16+h], W3[o*16+h2], g);
      sG[t] = g;
    }
    if (t < 16) {
      float r = 0.f;
      #pragma unroll
      for (int o = 0; o < 32; ++o) r = fmaf(W3[o*16+t], b3[o], r);
      sR[t] = r;
    }
    if (t == 0) {
      float bb3 = 0.f;
      for (int o = 0; o < 32; ++o) bb3 = fmaf(b3[o], b3[o], bb3);
      float wsum = 0.f;
      for (int k = 0; k < 16; ++k) wsum += Wb[k];
      ws[WS_SC + 0] = bb3;
      ws[WS_SC + 1] = wsum;
      *reinterpret_cast<double*>(ws + WS_ACC) = 0.0;

      float tb[16];                      // lrelu-mask breakpoints, clamp [-0.5,1.5]
      for (int hh = 0; hh < 16; ++hh) {
        float w = W2[hh], bv = b2[hh];
        float tt = (fabsf(w) > 1e-30f) ? (-bv / w) : ((bv > 0.f) ? -0.5f : 1.5f);
        tb[hh] = fminf(fmaxf(tt, -0.5f), 1.5f);
      }
      for (int a = 1; a < 16; ++a) {     // insertion sort, 16 elems
        float key = tb[a]; int c = a - 1;
        while (c >= 0 && tb[c] > key) { tb[c+1] = tb[c]; --c; }
        tb[c+1] = key;
      }
      for (int hh = 0; hh < 16; ++hh) { sTB[hh] = tb[hh]; ws[WS_SS + hh] = tb[hh]; }
    }
    __syncthreads();
    for (int idx = t; idx < 272; idx += 256) {   // per-interval masked weights
      int k = idx >> 4, hh = idx & 15;
      float lo = (k == 0)  ? sTB[0]  - 1.f : sTB[k-1];
      float hi = (k == 16) ? sTB[15] + 1.f : sTB[k];
      float zr = 0.5f * (lo + hi);
      float v = fmaf(zr, W2[hh], b2[hh]);
      float m = (v > 0.f) ? 1.f : 0.01f;
      float wmv = m * W2[hh], bmv = m * b2[hh];
      sWM[idx] = wmv; sBMk[idx] = bmv;
      ws[WS_WM  + idx] = wmv;
      ws[WS_BMK + idx] = bmv;
    }
    __syncthreads();
    if (t < 17) {                        // per-interval quadratic coefficients
      int k = t;
      float A = 0.f, Bq = 0.f, Cq = 0.f, wr = 0.f, br = 0.f;
      #pragma unroll
      for (int h = 0; h < 16; ++h) {
        float wm = sWM[k*16 + h], bm = sBMk[k*16 + h];
        float gw = 0.f, gb = 0.f;
        #pragma unroll
        for (int h2 = 0; h2 < 16; ++h2) {
          float g = sG[h*16 + h2];
          gw = fmaf(g, sWM[k*16 + h2],  gw);
          gb = fmaf(g, sBMk[k*16 + h2], gb);
        }
        A  = fmaf(wm, gw, A);
        Bq = fmaf(wm, gb, Bq);
        Cq = fmaf(bm, gb, Cq);
        wr = fmaf(wm, sR[h], wr);
        br = fmaf(bm, sR[h], br);
      }
      ws[WS_ABC + k*4 + 0] = A;
      ws[WS_ABC + k*4 + 1] = 2.f * (Bq + wr);
      ws[WS_ABC + k*4 + 2] = Cq + 2.f * br;
      ws[WS_ABC + k*4 + 3] = 0.f;
    }
    return;
  }
  int row = blockIdx.x * 256 + t;        // rows, blocks 0..12
  if (row >= B_ * N_) return;
  float xr[16];
  #pragma unroll
  for (int q = 0; q < 4; ++q) {
    float4 v = *reinterpret_cast<const float4*>(x + row*16 + q*4);
    xr[q*4+0] = v.x; xr[q*4+1] = v.y; xr[q*4+2] = v.z; xr[q*4+3] = v.w;
  }
  float h0[16];
  #pragma unroll
  for (int h = 0; h < 16; ++h) {
    float a = b_enc[h];
    #pragma unroll
    for (int k = 0; k < 16; ++k) a = fmaf(xr[k], W_enc[h*16+k], a);
    h0[h] = fmaxf(a, 0.01f * a);
  }
  #pragma unroll
  for (int h = 0; h < 16; ++h) {
    float a = b1[h], bm = 0.f;
    #pragma unroll
    for (int k = 0; k < 16; ++k) {
      a  = fmaf(h0[k], W1[h*32 + k],      a);
      bm = fmaf(h0[k], W1[h*32 + 16 + k], bm);
    }
    ws[WS_AP + row*16 + h] = a;
    ws[WS_BM + row*16 + h] = bm;
  }
  #pragma unroll
  for (int h = 0; h < 16; ++h) {
    float pp = 0.f, qq = 0.f;
    #pragma unroll
    for (int o = 0; o < 16; ++o) {
      pp = fmaf(W3[o*16 + h],      h0[o], pp);
      qq = fmaf(W3[(16+o)*16 + h], h0[o], qq);
    }
    ws[WS_P + row*16 + h] = pp;
    ws[WS_Q + row*16 + h] = qq;
  }
  float c1 = 0.f, c2 = 0.f, e = 0.f;
  #pragma unroll
  for (int o = 0; o < 16; ++o) {
    c1 = fmaf(b3[o],    h0[o], c1);
    c2 = fmaf(b3[16+o], h0[o], c2);
    e  = fmaf(h0[o],    h0[o], e);
  }
  ws[WS_D1 + row] = e - 2.f * c1;
  ws[WS_D2 + row] = e - 2.f * c2;
}

// -------- kernel 2: BN partials (0..399, direct-L2 Bm) + row projections (400..) --------
__global__ __launch_bounds__(256) void stats_proj_k(float* __restrict__ ws) {
  int t = threadIdx.x;
  int blk = blockIdx.x;
  if (blk >= 400) {                      // per-(row,interval) projections of P,Q
    int idx = (blk - 400) * 256 + t;
    if (idx >= 3200 * 17) return;
    int row = idx / 17, k = idx - row * 17;
    const float* wm = ws + WS_WM  + k*16;
    const float* bm = ws + WS_BMK + k*16;
    const float* Pr = ws + WS_P + row*16;
    const float* Qr = ws + WS_Q + row*16;
    float pw = 0.f, pb = 0.f, qw = 0.f, qb = 0.f;
    #pragma unroll
    for (int h = 0; h < 16; ++h) {
      float p = Pr[h], q = Qr[h], w = wm[h], b = bm[h];
      pw = fmaf(w, p, pw); pb = fmaf(b, p, pb);
      qw = fmaf(w, q, qw); qb = fmaf(b, q, qb);
    }
    ws[WS_PP + idx*2 + 0] = pw;
    ws[WS_PP + idx*2 + 1] = pb;
    ws[WS_QQ + idx*2 + 0] = qw;
    ws[WS_QQ + idx*2 + 1] = qb;
    return;
  }
  // BN partial: block = (i-tile of 16) x (j-slice of 100); Bm read direct from L2
  __shared__ __align__(16) float sAt[4][16][16];     // 4 KB only -> high occupancy
  int it = blk >> 3, js = blk & 7;
  int i0 = it * 16, jbase = js * 100;
  {
    int b = t >> 6, r = t & 63;                      // 256 float4 for the A tile
    reinterpret_cast<float4*>(&sAt[0][0][0])[t] =
        *reinterpret_cast<const float4*>(ws + WS_AP + (b*N_ + i0)*16 + r*4);
  }
  __syncthreads();
  int il = t >> 4, jt = t & 15;
  float a[4][16];
  #pragma unroll
  for (int b = 0; b < 4; ++b)
    #pragma unroll
    for (int h = 0; h < 16; ++h) a[b][h] = sAt[b][il][h];   // LDS broadcast
  float s = 0.f, s2 = 0.f;
  #pragma unroll
  for (int jj = 0; jj < 7; ++jj) {
    int j = jt + jj*16;
    if (j < 100) {
      #pragma unroll
      for (int b = 0; b < 4; ++b) {
        #pragma unroll
        for (int q = 0; q < 4; ++q) {
          float4 bm = *reinterpret_cast<const float4*>(
              ws + WS_BM + (b*N_ + jbase + j)*16 + q*4);   // L2-resident
          float v;
          v = fmaxf(a[b][q*4+0] + bm.x, 0.f); s += v; s2 = fmaf(v, v, s2);
          v = fmaxf(a[b][q*4+1] + bm.y, 0.f); s += v; s2 = fmaf(v, v, s2);
          v = fmaxf(a[b][q*4+2] + bm.z, 0.f); s += v; s2 = fmaf(v, v, s2);
          v = fmaxf(a[b][q*4+3] + bm.w, 0.f); s += v; s2 = fmaf(v, v, s2);
        }
      }
    }
  }
  #pragma unroll
  for (int off = 8; off; off >>= 1) {                // reduce within 16-lane group
    s  += __shfl_down(s,  off, 16);
    s2 += __shfl_down(s2, off, 16);
  }
  if (jt == 0) {
    atomicAdd(ws + WS_S  + i0 + il, s);
    atomicAdd(ws + WS_S2 + i0 + il, s2);
  }
}

// ------- kernel 3: main 32x32 pair kernel (low-LDS) + ticket-fused loss finalize -------
__global__ __launch_bounds__(256) void pair_k(
    const float* __restrict__ u, const float* __restrict__ Wb,
    const float* __restrict__ bn_w, const float* __restrict__ bn_b,
    const float* __restrict__ bb, float* __restrict__ ws,
    float* __restrict__ out, double* __restrict__ acc) {
  __shared__ __align__(16) float sAp[4][32][16];   // b128 broadcast reads: no pad needed
  __shared__ __align__(16) float sBm[4][32][17];   // stride 17: scalar reads conflict-free
  __shared__ __align__(16) float4 sABC[17];
  __shared__ float sd1[4][32], sd2[4][32];
  __shared__ float sAl[32], sBe[32];
  __shared__ float red[4];
  __shared__ float sbb3;

  int t  = threadIdx.x;
  int bi = blockIdx.x % 25, bj = blockIdx.x / 25;
  int i0 = bi * 32, j0 = bj * 32;
  int li = t >> 4, lj = t & 15;

  // u prefetch: 16 independent HBM loads in flight during LDS staging
  float ur[16];
  #pragma unroll
  for (int b = 0; b < 4; ++b)
    #pragma unroll
    for (int di = 0; di < 2; ++di)
      #pragma unroll
      for (int dj = 0; dj < 2; ++dj)
        ur[b*4 + di*2 + dj] = u[(b*N_ + i0 + li + di*16)*N_ + j0 + lj + dj*16];

  {
    float4* dAp = reinterpret_cast<float4*>(&sAp[0][0][0]);
    for (int idx = t; idx < 512; idx += 256) {       // LDS layout == global layout
      int b = idx >> 7, r = idx & 127;
      dAp[idx] = *reinterpret_cast<const float4*>(ws + WS_AP + (b*N_ + i0)*16 + r*4);
    }
    for (int idx = t; idx < 2048; idx += 256) {      // sBm stride-17 scatter
      int b = idx >> 9, r = idx & 511;
      int l = r >> 4, h = r & 15;
      sBm[b][l][h] = ws[WS_BM + (b*N_ + j0 + l)*16 + h];
    }
  }
  if (t < 68) reinterpret_cast<float*>(sABC)[t] = ws[WS_ABC + t];
  if (t < 128) {
    sd1[t >> 5][t & 31] = ws[WS_D1 + (t >> 5)*N_ + i0 + (t & 31)];
    sd2[t >> 5][t & 31] = ws[WS_D2 + (t >> 5)*N_ + j0 + (t & 31)];
  }
  if (t < 32) {                                      // BN finalize, folded in
    float s = ws[WS_S + i0 + t], s2 = ws[WS_S2 + i0 + t];
    const float inv = 1.0f / 51200.0f;
    float mean = s * inv;
    float var  = s2 * inv - mean * mean;
    float rstd = 1.0f / sqrtf(var + 1e-5f);
    float al = bn_w[i0 + t] * rstd;
    float wsum = ws[WS_SC + 1];
    sAl[t] = al;
    sBe[t] = fmaf(-al * mean, wsum, fmaf(bn_b[i0 + t], wsum, bb[0]));
  }
  if (t == 0) sbb3 = ws[WS_SC + 0];
  float ssr[16], wbr[16];                            // uniform -> SGPRs
  #pragma unroll
  for (int h = 0; h < 16; ++h) ssr[h] = ws[WS_SS + h];
  #pragma unroll
  for (int h = 0; h < 16; ++h) wbr[h] = Wb[h];
  __syncthreads();

  float al0 = sAl[li], be0 = sBe[li], al1 = sAl[li+16], be1 = sBe[li+16];
  const float* ppb0 = ws + WS_PP + (i0 + li)*34;
  const float* qqb0 = ws + WS_QQ + (j0 + lj)*34;
  float zsum[4] = {0.f, 0.f, 0.f, 0.f};
  float Lacc = 0.f;

  #pragma unroll
  for (int b = 0; b < 4; ++b) {
    float Af[2][16], Mf[2][16];
    #pragma unroll
    for (int d = 0; d < 2; ++d) {
      #pragma unroll
      for (int q = 0; q < 4; ++q) {                  // b128 broadcast (2-way: free)
        float4 va = *reinterpret_cast<const float4*>(&sAp[b][li + d*16][q*4]);
        Af[d][q*4+0] = va.x; Af[d][q*4+1] = va.y; Af[d][q*4+2] = va.z; Af[d][q*4+3] = va.w;
      }
      #pragma unroll
      for (int h = 0; h < 16; ++h)                   // stride-17: conflict-free
        Mf[d][h] = sBm[b][lj + d*16][h];
    }
    #pragma unroll
    for (int di = 0; di < 2; ++di) {
      #pragma unroll
      for (int dj = 0; dj < 2; ++dj) {
        float S = 0.f;
        #pragma unroll
        for (int h = 0; h < 16; ++h) {
          float v = fmaxf(Af[di][h] + Mf[dj][h], 0.f);
          S = fmaf(v, wbr[h], S);
        }
        // logits == xl exactly (log(sigmoid x) - log1p(-sigmoid x) == x)
        float xl = fmaf(di ? al1 : al0, S, di ? be1 : be0);
        float uu = ur[b*4 + di*2 + dj];
        float noise = __logf(uu) - __logf(1.0f - uu);
        float z = __fdividef(1.0f, 1.0f + __expf((xl + noise) * -5.0f));
        zsum[di*2 + dj] += z;
        int kx2 = 0;                                 // 2*interval index
        #pragma unroll
        for (int h = 0; h < 16; ++h) kx2 += (z > ssr[h]) ? 2 : 0;
        float4 abc = sABC[kx2 >> 1];
        float2 pp = *reinterpret_cast<const float2*>(ppb0 + (b*N_ + di*16)*34 + kx2);
        float2 qq = *reinterpret_cast<const float2*>(qqb0 + (b*N_ + dj*16)*34 + kx2);
        Lacc += fmaf(abc.x, z*z, fmaf(abc.y, z, abc.z))
              - 2.f * fmaf(z, pp.x + qq.x, pp.y + qq.y);
      }
    }
  }
  // hoisted constant terms: each d1[b][i-row] / d2[b][j-col] appears twice
  #pragma unroll
  for (int b = 0; b < 4; ++b)
    Lacc += 2.f * (sd1[b][li] + sd1[b][li+16] + sd2[b][lj] + sd2[b][lj+16]);
  Lacc += 16.f * sbb3;

  #pragma unroll
  for (int di = 0; di < 2; ++di)
    #pragma unroll
    for (int dj = 0; dj < 2; ++dj)
      out[(i0 + li + di*16)*N_ + j0 + lj + dj*16] = zsum[di*2 + dj] * 0.25f;

  #pragma unroll
  for (int off = 32; off; off >>= 1) Lacc += __shfl_down(Lacc, off);
  if ((t & 63) == 0) red[t >> 6] = Lacc;
  __syncthreads();
  if (t == 0) {
    atomicAdd(acc, (double)(red[0] + red[1] + red[2] + red[3]));
    __threadfence();                     // order acc add before ticket increment
    unsigned old = atomicAdd(reinterpret_cast<unsigned*>(ws + WS_TK), 1u);
    if (old == 624u) {                   // last block finalizes (passed in round 3)
      double v = atomicAdd(acc, 0.0);    // device-scope coherent read of all adds
      out[N_ * N_] = (float)(v * (1.0 / (4.0 * 800.0 * 800.0 * 32.0)));
    }
  }
}

extern "C" void kernel_launch(void* const* d_in, const int* in_sizes, int n_in,
                              void* d_out, int out_size, void* d_ws, size_t ws_size,
                              hipStream_t stream) {
  const float* x     = (const float*)d_in[0];
  const float* u     = (const float*)d_in[1];
  const float* W_enc = (const float*)d_in[2];
  const float* b_enc = (const float*)d_in[3];
  const float* W1    = (const float*)d_in[4];
  const float* b1    = (const float*)d_in[5];
  const float* Wb    = (const float*)d_in[6];
  const float* bb    = (const float*)d_in[7];
  // d_in[8..11] = Wmu, bmu, Wlv, blv — dead code in the reference
  const float* bn_w  = (const float*)d_in[12];
  const float* bn_b  = (const float*)d_in[13];
  const float* W2    = (const float*)d_in[14];
  const float* b2    = (const float*)d_in[15];
  const float* W3    = (const float*)d_in[16];
  const float* b3    = (const float*)d_in[17];

  float*  out = (float*)d_out;
  float*  ws  = (float*)d_ws;
  double* acc = (double*)(ws + WS_ACC);

  prep_k      <<<15,  256, 0, stream>>>(x, W_enc, b_enc, W1, b1, Wb, b3, W3, W2, b2, ws);
  stats_proj_k<<<613, 256, 0, stream>>>(ws);
  pair_k      <<<625, 256, 0, stream>>>(u, Wb, bn_w, bn_b, bb, ws, out, acc);
}

// Round 13
// 146.010 us; speedup vs baseline: 1.0603x; 1.0603x over previous
//
#include <hip/hip_runtime.h>
#include <math.h>

#define B_ 4
#define N_ 800
#define H_ 16

// ---- workspace layout (float indices) ----
#define WS_AP   0         // A' = h0*W1[:, :H] + b1      [4*800*16]
#define WS_BM   51200     // Bm = h0*W1[:, H:]           [4*800*16]
#define WS_P    102400    // P  = W3[:16,:]^T h0         [4*800*16]
#define WS_Q    153600    // Q  = W3[16:,:]^T h0         [4*800*16]
#define WS_D1   204800    // e - 2*c1                    [3200]
#define WS_D2   208000    // e - 2*c2                    [3200]
#define WS_S    211200    // BN sum  per channel i       [800]
#define WS_S2   212000    // BN sum2 per channel i       [800]
#define WS_SC   213072    // [0]=||b3||^2 [1]=sum(Wb)
#define WS_SS   213074    // sorted breakpoints          [16]
#define WS_WM   213090    // wm[k][h] = m*W2             [17*16]
#define WS_BMK  213362    // bm[k][h] = m*b2             [17*16]
#define WS_ABC  213634    // A,B,C,pad per interval      [17*4]
#define WS_PP   213702    // (PW,Pb) per (row,k)         [3200*17*2]
#define WS_QQ   322502    // (QW,Qb) per (row,k)         [3200*17*2]
#define WS_ACC  431302    // double loss accumulator (431302*4 % 8 == 0)

// ---------------- kernel 1: per-row prep + weight tables + ws zeroing ----------------
__global__ __launch_bounds__(256) void prep_k(
    const float* __restrict__ x, const float* __restrict__ W_enc,
    const float* __restrict__ b_enc, const float* __restrict__ W1,
    const float* __restrict__ b1, const float* __restrict__ Wb,
    const float* __restrict__ b3, const float* __restrict__ W3,
    const float* __restrict__ W2, const float* __restrict__ b2,
    float* __restrict__ ws) {
  int t = threadIdx.x;
  if (blockIdx.x == 14) {               // zero BN accumulators (ws is poisoned)
    for (int i = t; i < 1600; i += 256) ws[WS_S + i] = 0.f;
    return;
  }
  if (blockIdx.x == 13) {               // weights-derived constants (whole block)
    __shared__ float sG[256], sR[16], sTB[16];
    __shared__ float sWM[272], sBMk[272];
    {
      int h = t >> 4, h2 = t & 15;
      float g = 0.f;
      #pragma unroll
      for (int o = 0; o < 32; ++o) g = fmaf(W3[o*16+h], W3[o*16+h2], g);
      sG[t] = g;
    }
    if (t < 16) {
      float r = 0.f;
      #pragma unroll
      for (int o = 0; o < 32; ++o) r = fmaf(W3[o*16+t], b3[o], r);
      sR[t] = r;
    }
    if (t == 0) {
      float bb3 = 0.f;
      for (int o = 0; o < 32; ++o) bb3 = fmaf(b3[o], b3[o], bb3);
      float wsum = 0.f;
      for (int k = 0; k < 16; ++k) wsum += Wb[k];
      ws[WS_SC + 0] = bb3;
      ws[WS_SC + 1] = wsum;
      *reinterpret_cast<double*>(ws + WS_ACC) = 0.0;

      float tb[16];                      // lrelu-mask breakpoints, clamp [-0.5,1.5]
      for (int hh = 0; hh < 16; ++hh) {
        float w = W2[hh], bv = b2[hh];
        float tt = (fabsf(w) > 1e-30f) ? (-bv / w) : ((bv > 0.f) ? -0.5f : 1.5f);
        tb[hh] = fminf(fmaxf(tt, -0.5f), 1.5f);
      }
      for (int a = 1; a < 16; ++a) {     // insertion sort, 16 elems
        float key = tb[a]; int c = a - 1;
        while (c >= 0 && tb[c] > key) { tb[c+1] = tb[c]; --c; }
        tb[c+1] = key;
      }
      for (int hh = 0; hh < 16; ++hh) { sTB[hh] = tb[hh]; ws[WS_SS + hh] = tb[hh]; }
    }
    __syncthreads();
    for (int idx = t; idx < 272; idx += 256) {   // per-interval masked weights
      int k = idx >> 4, hh = idx & 15;
      float lo = (k == 0)  ? sTB[0]  - 1.f : sTB[k-1];
      float hi = (k == 16) ? sTB[15] + 1.f : sTB[k];
      float zr = 0.5f * (lo + hi);
      float v = fmaf(zr, W2[hh], b2[hh]);
      float m = (v > 0.f) ? 1.f : 0.01f;
      float wmv = m * W2[hh], bmv = m * b2[hh];
      sWM[idx] = wmv; sBMk[idx] = bmv;
      ws[WS_WM  + idx] = wmv;
      ws[WS_BMK + idx] = bmv;
    }
    __syncthreads();
    if (t < 17) {                        // per-interval quadratic coefficients
      int k = t;
      float A = 0.f, Bq = 0.f, Cq = 0.f, wr = 0.f, br = 0.f;
      #pragma unroll
      for (int h = 0; h < 16; ++h) {
        float wm = sWM[k*16 + h], bm = sBMk[k*16 + h];
        float gw = 0.f, gb = 0.f;
        #pragma unroll
        for (int h2 = 0; h2 < 16; ++h2) {
          float g = sG[h*16 + h2];
          gw = fmaf(g, sWM[k*16 + h2],  gw);
          gb = fmaf(g, sBMk[k*16 + h2], gb);
        }
        A  = fmaf(wm, gw, A);
        Bq = fmaf(wm, gb, Bq);
        Cq = fmaf(bm, gb, Cq);
        wr = fmaf(wm, sR[h], wr);
        br = fmaf(bm, sR[h], br);
      }
      ws[WS_ABC + k*4 + 0] = A;
      ws[WS_ABC + k*4 + 1] = 2.f * (Bq + wr);
      ws[WS_ABC + k*4 + 2] = Cq + 2.f * br;
      ws[WS_ABC + k*4 + 3] = 0.f;
    }
    return;
  }
  int row = blockIdx.x * 256 + t;        // rows, blocks 0..12
  if (row >= B_ * N_) return;
  float xr[16];
  #pragma unroll
  for (int q = 0; q < 4; ++q) {
    float4 v = *reinterpret_cast<const float4*>(x + row*16 + q*4);
    xr[q*4+0] = v.x; xr[q*4+1] = v.y; xr[q*4+2] = v.z; xr[q*4+3] = v.w;
  }
  float h0[16];
  #pragma unroll
  for (int h = 0; h < 16; ++h) {
    float a = b_enc[h];
    #pragma unroll
    for (int k = 0; k < 16; ++k) a = fmaf(xr[k], W_enc[h*16+k], a);
    h0[h] = fmaxf(a, 0.01f * a);
  }
  #pragma unroll
  for (int h = 0; h < 16; ++h) {
    float a = b1[h], bm = 0.f;
    #pragma unroll
    for (int k = 0; k < 16; ++k) {
      a  = fmaf(h0[k], W1[h*32 + k],      a);
      bm = fmaf(h0[k], W1[h*32 + 16 + k], bm);
    }
    ws[WS_AP + row*16 + h] = a;
    ws[WS_BM + row*16 + h] = bm;
  }
  #pragma unroll
  for (int h = 0; h < 16; ++h) {
    float pp = 0.f, qq = 0.f;
    #pragma unroll
    for (int o = 0; o < 16; ++o) {
      pp = fmaf(W3[o*16 + h],      h0[o], pp);
      qq = fmaf(W3[(16+o)*16 + h], h0[o], qq);
    }
    ws[WS_P + row*16 + h] = pp;
    ws[WS_Q + row*16 + h] = qq;
  }
  float c1 = 0.f, c2 = 0.f, e = 0.f;
  #pragma unroll
  for (int o = 0; o < 16; ++o) {
    c1 = fmaf(b3[o],    h0[o], c1);
    c2 = fmaf(b3[16+o], h0[o], c2);
    e  = fmaf(h0[o],    h0[o], e);
  }
  ws[WS_D1 + row] = e - 2.f * c1;
  ws[WS_D2 + row] = e - 2.f * c2;
}

// -------- kernel 2: BN partials (0..399, direct-L2 Bm) + row projections (400..) --------
__global__ __launch_bounds__(256) void stats_proj_k(float* __restrict__ ws) {
  int t = threadIdx.x;
  int blk = blockIdx.x;
  if (blk >= 400) {                      // per-(row,interval) projections of P,Q
    int idx = (blk - 400) * 256 + t;
    if (idx >= 3200 * 17) return;
    int row = idx / 17, k = idx - row * 17;
    const float* wm = ws + WS_WM  + k*16;
    const float* bm = ws + WS_BMK + k*16;
    const float* Pr = ws + WS_P + row*16;
    const float* Qr = ws + WS_Q + row*16;
    float pw = 0.f, pb = 0.f, qw = 0.f, qb = 0.f;
    #pragma unroll
    for (int h = 0; h < 16; ++h) {
      float p = Pr[h], q = Qr[h], w = wm[h], b = bm[h];
      pw = fmaf(w, p, pw); pb = fmaf(b, p, pb);
      qw = fmaf(w, q, qw); qb = fmaf(b, q, qb);
    }
    ws[WS_PP + idx*2 + 0] = pw;
    ws[WS_PP + idx*2 + 1] = pb;
    ws[WS_QQ + idx*2 + 0] = qw;
    ws[WS_QQ + idx*2 + 1] = qb;
    return;
  }
  // BN partial: block = (i-tile of 16) x (j-slice of 100); Bm read direct from L2
  __shared__ __align__(16) float sAt[4][16][16];     // 4 KB only -> high occupancy
  int it = blk >> 3, js = blk & 7;
  int i0 = it * 16, jbase = js * 100;
  {
    int b = t >> 6, r = t & 63;                      // 256 float4 for the A tile
    reinterpret_cast<float4*>(&sAt[0][0][0])[t] =
        *reinterpret_cast<const float4*>(ws + WS_AP + (b*N_ + i0)*16 + r*4);
  }
  __syncthreads();
  int il = t >> 4, jt = t & 15;
  float a[4][16];
  #pragma unroll
  for (int b = 0; b < 4; ++b)
    #pragma unroll
    for (int h = 0; h < 16; ++h) a[b][h] = sAt[b][il][h];   // LDS broadcast
  float s = 0.f, s2 = 0.f;
  #pragma unroll
  for (int jj = 0; jj < 7; ++jj) {
    int j = jt + jj*16;
    if (j < 100) {
      #pragma unroll
      for (int b = 0; b < 4; ++b) {
        #pragma unroll
        for (int q = 0; q < 4; ++q) {
          float4 bm = *reinterpret_cast<const float4*>(
              ws + WS_BM + (b*N_ + jbase + j)*16 + q*4);   // L2-resident
          float v;
          v = fmaxf(a[b][q*4+0] + bm.x, 0.f); s += v; s2 = fmaf(v, v, s2);
          v = fmaxf(a[b][q*4+1] + bm.y, 0.f); s += v; s2 = fmaf(v, v, s2);
          v = fmaxf(a[b][q*4+2] + bm.z, 0.f); s += v; s2 = fmaf(v, v, s2);
          v = fmaxf(a[b][q*4+3] + bm.w, 0.f); s += v; s2 = fmaf(v, v, s2);
        }
      }
    }
  }
  #pragma unroll
  for (int off = 8; off; off >>= 1) {                // reduce within 16-lane group
    s  += __shfl_down(s,  off, 16);
    s2 += __shfl_down(s2, off, 16);
  }
  if (jt == 0) {
    atomicAdd(ws + WS_S  + i0 + il, s);
    atomicAdd(ws + WS_S2 + i0 + il, s2);
  }
}

// ---------------- kernel 3: main 32x32 pair kernel (low-LDS, high-occupancy) ----------------
__global__ __launch_bounds__(256) void pair_k(
    const float* __restrict__ u, const float* __restrict__ Wb,
    const float* __restrict__ bn_w, const float* __restrict__ bn_b,
    const float* __restrict__ bb, const float* __restrict__ ws,
    float* __restrict__ out, double* __restrict__ acc) {
  __shared__ __align__(16) float sAp[4][32][16];   // b128 broadcast reads: no pad needed
  __shared__ __align__(16) float sBm[4][32][17];   // stride 17: scalar reads conflict-free
  __shared__ __align__(16) float4 sABC[17];
  __shared__ float sd1[4][32], sd2[4][32];
  __shared__ float sAl[32], sBe[32];
  __shared__ float red[4];
  __shared__ float sbb3;

  int t  = threadIdx.x;
  int bi = blockIdx.x % 25, bj = blockIdx.x / 25;
  int i0 = bi * 32, j0 = bj * 32;
  int li = t >> 4, lj = t & 15;

  // u prefetch: 16 independent HBM loads in flight during LDS staging
  float ur[16];
  #pragma unroll
  for (int b = 0; b < 4; ++b)
    #pragma unroll
    for (int di = 0; di < 2; ++di)
      #pragma unroll
      for (int dj = 0; dj < 2; ++dj)
        ur[b*4 + di*2 + dj] = u[(b*N_ + i0 + li + di*16)*N_ + j0 + lj + dj*16];

  {
    float4* dAp = reinterpret_cast<float4*>(&sAp[0][0][0]);
    for (int idx = t; idx < 512; idx += 256) {       // LDS layout == global layout
      int b = idx >> 7, r = idx & 127;
      dAp[idx] = *reinterpret_cast<const float4*>(ws + WS_AP + (b*N_ + i0)*16 + r*4);
    }
    for (int idx = t; idx < 2048; idx += 256) {      // sBm stride-17 scatter
      int b = idx >> 9, r = idx & 511;
      int l = r >> 4, h = r & 15;
      sBm[b][l][h] = ws[WS_BM + (b*N_ + j0 + l)*16 + h];
    }
  }
  if (t < 68) reinterpret_cast<float*>(sABC)[t] = ws[WS_ABC + t];
  if (t < 128) {
    sd1[t >> 5][t & 31] = ws[WS_D1 + (t >> 5)*N_ + i0 + (t & 31)];
    sd2[t >> 5][t & 31] = ws[WS_D2 + (t >> 5)*N_ + j0 + (t & 31)];
  }
  if (t < 32) {                                      // BN finalize, folded in
    float s = ws[WS_S + i0 + t], s2 = ws[WS_S2 + i0 + t];
    const float inv = 1.0f / 51200.0f;
    float mean = s * inv;
    float var  = s2 * inv - mean * mean;
    float rstd = 1.0f / sqrtf(var + 1e-5f);
    float al = bn_w[i0 + t] * rstd;
    float wsum = ws[WS_SC + 1];
    sAl[t] = al;
    sBe[t] = fmaf(-al * mean, wsum, fmaf(bn_b[i0 + t], wsum, bb[0]));
  }
  if (t == 0) sbb3 = ws[WS_SC + 0];
  float ssr[16], wbr[16];                            // uniform -> SGPRs
  #pragma unroll
  for (int h = 0; h < 16; ++h) ssr[h] = ws[WS_SS + h];
  #pragma unroll
  for (int h = 0; h < 16; ++h) wbr[h] = Wb[h];
  __syncthreads();

  float al0 = sAl[li], be0 = sBe[li], al1 = sAl[li+16], be1 = sBe[li+16];
  const float* ppb0 = ws + WS_PP + (i0 + li)*34;
  const float* qqb0 = ws + WS_QQ + (j0 + lj)*34;
  float zsum[4] = {0.f, 0.f, 0.f, 0.f};
  float Lacc = 0.f;

  #pragma unroll
  for (int b = 0; b < 4; ++b) {
    float Af[2][16], Mf[2][16];
    #pragma unroll
    for (int d = 0; d < 2; ++d) {
      #pragma unroll
      for (int q = 0; q < 4; ++q) {                  // b128 broadcast (2-way: free)
        float4 va = *reinterpret_cast<const float4*>(&sAp[b][li + d*16][q*4]);
        Af[d][q*4+0] = va.x; Af[d][q*4+1] = va.y; Af[d][q*4+2] = va.z; Af[d][q*4+3] = va.w;
      }
      #pragma unroll
      for (int h = 0; h < 16; ++h)                   // stride-17: conflict-free
        Mf[d][h] = sBm[b][lj + d*16][h];
    }
    #pragma unroll
    for (int di = 0; di < 2; ++di) {
      #pragma unroll
      for (int dj = 0; dj < 2; ++dj) {
        float S = 0.f;
        #pragma unroll
        for (int h = 0; h < 16; ++h) {
          float v = fmaxf(Af[di][h] + Mf[dj][h], 0.f);
          S = fmaf(v, wbr[h], S);
        }
        // logits == xl exactly (log(sigmoid x) - log1p(-sigmoid x) == x)
        float xl = fmaf(di ? al1 : al0, S, di ? be1 : be0);
        float uu = ur[b*4 + di*2 + dj];
        float noise = __logf(uu) - __logf(1.0f - uu);
        float z = __fdividef(1.0f, 1.0f + __expf((xl + noise) * -5.0f));
        zsum[di*2 + dj] += z;
        int kx2 = 0;                                 // 2*interval index
        #pragma unroll
        for (int h = 0; h < 16; ++h) kx2 += (z > ssr[h]) ? 2 : 0;
        float4 abc = sABC[kx2 >> 1];
        float2 pp = *reinterpret_cast<const float2*>(ppb0 + (b*N_ + di*16)*34 + kx2);
        float2 qq = *reinterpret_cast<const float2*>(qqb0 + (b*N_ + dj*16)*34 + kx2);
        Lacc += fmaf(abc.x, z*z, fmaf(abc.y, z, abc.z))
              - 2.f * fmaf(z, pp.x + qq.x, pp.y + qq.y);
      }
    }
  }
  // hoisted constant terms: each d1[b][i-row] / d2[b][j-col] appears twice
  #pragma unroll
  for (int b = 0; b < 4; ++b)
    Lacc += 2.f * (sd1[b][li] + sd1[b][li+16] + sd2[b][lj] + sd2[b][lj+16]);
  Lacc += 16.f * sbb3;

  #pragma unroll
  for (int di = 0; di < 2; ++di)
    #pragma unroll
    for (int dj = 0; dj < 2; ++dj)
      out[(i0 + li + di*16)*N_ + j0 + lj + dj*16] = zsum[di*2 + dj] * 0.25f;

  #pragma unroll
  for (int off = 32; off; off >>= 1) Lacc += __shfl_down(Lacc, off);
  if ((t & 63) == 0) red[t >> 6] = Lacc;
  __syncthreads();
  if (t == 0) atomicAdd(acc, (double)(red[0] + red[1] + red[2] + red[3]));
}

// ---------------- kernel 4: finalize loss ----------------
__global__ void fin_k(const double* __restrict__ acc, float* __restrict__ out) {
  out[N_ * N_] = (float)(*acc * (1.0 / (4.0 * 800.0 * 800.0 * 32.0)));
}

extern "C" void kernel_launch(void* const* d_in, const int* in_sizes, int n_in,
                              void* d_out, int out_size, void* d_ws, size_t ws_size,
                              hipStream_t stream) {
  const float* x     = (const float*)d_in[0];
  const float* u     = (const float*)d_in[1];
  const float* W_enc = (const float*)d_in[2];
  const float* b_enc = (const float*)d_in[3];
  const float* W1    = (const float*)d_in[4];
  const float* b1    = (const float*)d_in[5];
  const float* Wb    = (const float*)d_in[6];
  const float* bb    = (const float*)d_in[7];
  // d_in[8..11] = Wmu, bmu, Wlv, blv — dead code in the reference
  const float* bn_w  = (const float*)d_in[12];
  const float* bn_b  = (const float*)d_in[13];
  const float* W2    = (const float*)d_in[14];
  const float* b2    = (const float*)d_in[15];
  const float* W3    = (const float*)d_in[16];
  const float* b3    = (const float*)d_in[17];

  float*  out = (float*)d_out;
  float*  ws  = (float*)d_ws;
  double* acc = (double*)(ws + WS_ACC);

  prep_k      <<<15,  256, 0, stream>>>(x, W_enc, b_enc, W1, b1, Wb, b3, W3, W2, b2, ws);
  stats_proj_k<<<613, 256, 0, stream>>>(ws);
  pair_k      <<<625, 256, 0, stream>>>(u, Wb, bn_w, bn_b, bb, ws, out, acc);
  fin_k       <<<1,   1,   0, stream>>>(acc, out);
}